// Round 4
// baseline (1221.154 us; speedup 1.0000x reference)
//
#include <hip/hip_runtime.h>

typedef float f32x4 __attribute__((ext_vector_type(4)));
typedef _Float16 f16x8 __attribute__((ext_vector_type(8)));
typedef _Float16 f16x4 __attribute__((ext_vector_type(4)));
typedef int i32x4 __attribute__((ext_vector_type(4)));
typedef int i32x2 __attribute__((ext_vector_type(2)));

#define B_TOT   1024
#define D_DIM   128
#define N_STEPS 500
#define ROWS    4
#define WAVES   8

#define HSTRIDE 272                  // bytes per hist row (128 f16 + pad)
#define HSLOT   (8 * HSTRIDE)        // 8 rows (hi b0-3, lo b0-3) per slot
#define SLAB    (11 * HSLOT)         // slab base byte offset
#define SWSTR   2112                 // slab wave stride  (4 * 528)
#define SBSTR   528                  // slab batch stride (132 f32)
#define LDSSZ   (SLAB + WAVES * SWSTR)

static __device__ __forceinline__ float tanh_fast(float x) {
    float e = __builtin_amdgcn_exp2f(x * 2.885390081777927f);
    return 1.0f - 2.0f * __builtin_amdgcn_rcpf(e + 1.0f);
}
// c[lane] + c[lane^8]  via DPP row_ror:8 (VALU pipe, not DS)
static __device__ __forceinline__ float xor8_add(float x) {
    int xi = __builtin_bit_cast(int, x);
    int yi = __builtin_amdgcn_update_dpp(xi, xi, 0x128, 0xF, 0xF, false);
    return x + __builtin_bit_cast(float, yi);
}

__global__ __launch_bounds__(512, 2) void ndde_kernel(
    const float* __restrict__ x0, const float* __restrict__ tau,
    const float* __restrict__ W1, const float* __restrict__ b1,
    const float* __restrict__ W2, const float* __restrict__ b2,
    float* __restrict__ out)
{
    __shared__ __align__(16) char smem[LDSSZ];

    const int tid = threadIdx.x;
    const int w   = tid >> 6;
    const int l   = tid & 63;
    const int g   = l >> 4;
    const int l15 = l & 15;
    const int b_l = l15 & 3;                    // batch of this B-col
    const int ur  = b_l + 4 * (l15 >> 3);       // hist storage row (hi/lo)
    const int msel = l15 >> 2;                  // slab-write mt duty
    const int r0  = blockIdx.x * ROWS;
    // reduce-phase identity: one (batch, d) per thread
    const int rb  = tid >> 7;
    const int rd  = tid & 127;

    const float dtv = tau[0] * 0.1f;

    // ---------------- weights -> registers (fp16, remat-proof) ----------------
    i32x4 w1s[4][8];   // W1 A-frags: [nt over 64 h][ks over K=256]
    i32x2 w2s[8][4];   // W2 A-frags: [mt over 128 d][s over own 64-h chunk]
    i32x2 wbs[4];      // bias A-frags {w1t_hi, w1t_lo, w1t_hi, b1}

#pragma unroll
    for (int nt = 0; nt < 4; ++nt) {
        const int hr = 64 * w + 16 * nt + l15;
        const float* wr = W1 + (long)hr * 257;
#pragma unroll
        for (int ks = 0; ks < 8; ++ks) {
            const int c0 = 32 * ks + 8 * g;
            f16x8 f;
#pragma unroll
            for (int j = 0; j < 8; ++j) f[j] = (_Float16)wr[c0 + j];
            w1s[nt][ks] = __builtin_bit_cast(i32x4, f);
        }
        float wt = wr[256];
        _Float16 wh = (_Float16)wt;
        _Float16 wl = (_Float16)(wt - (float)wh);
        f16x4 ab = (g == 0) ? (f16x4){wh, wl, wh, (_Float16)b1[hr]}
                            : (f16x4){(_Float16)0.f, (_Float16)0.f, (_Float16)0.f, (_Float16)0.f};
        wbs[nt] = __builtin_bit_cast(i32x2, ab);
    }
#pragma unroll
    for (int mt = 0; mt < 8; ++mt) {
        const float* wr = W2 + (long)(16 * mt + l15) * 512;
#pragma unroll
        for (int s = 0; s < 4; ++s) {
            const int c0 = 64 * w + 16 * s + 4 * g;
            f16x4 f;
#pragma unroll
            for (int j = 0; j < 4; ++j) f[j] = (_Float16)wr[c0 + j];
            w2s[mt][s] = __builtin_bit_cast(i32x2, f);
        }
    }
    // opaque: values now defined by asm -> compiler cannot re-load/remat in loop
#pragma unroll
    for (int nt = 0; nt < 4; ++nt) {
#pragma unroll
        for (int ks = 0; ks < 8; ++ks) asm volatile("" : "+v"(w1s[nt][ks]));
        asm volatile("" : "+v"(wbs[nt]));
    }
#pragma unroll
    for (int mt = 0; mt < 8; ++mt)
#pragma unroll
        for (int s = 0; s < 4; ++s) asm volatile("" : "+v"(w2s[mt][s]));

    const float b2v = b2[rd];
    float xo = x0[(long)(r0 + rb) * D_DIM + rd];     // lane-owned state (r=rb, d=rd)

    // ---------------- init hist ring + out[0] ----------------
    {
        _Float16 hh = (_Float16)xo;
        _Float16 hl = (_Float16)(xo - (float)hh);
        for (int s = 0; s < 11; ++s) {
            *(short*)(smem + s * HSLOT + rb * HSTRIDE + 2 * rd)               = __builtin_bit_cast(short, hh);
            *(short*)(smem + s * HSLOT + (rb + 4) * HSTRIDE + 2 * rd)         = __builtin_bit_cast(short, hl);
        }
        out[(long)(r0 + rb) * D_DIM + rd] = xo;
    }
    __syncthreads();

    // invariant offsets
    const int histRd  = ur * HSTRIDE + 16 * g;                 // + slot*HSLOT + 64*ks
    const int slabWr  = SLAB + w * SWSTR + b_l * SBSTR + 64 * msel + 16 * g;  // + half*256
    const int slabRd  = SLAB + rb * SBSTR + 4 * rd;            // + wv*SWSTR
    const int histWr  = rb * HSTRIDE + 2 * rd;                 // + slot*HSLOT (+4*HSTRIDE for lo)
    const long outIdx = (long)(r0 + rb) * D_DIM + rd;

    int cur = 0;   // slot of x_n
    int ys  = 1;   // slot of y = x_{n-10}; rewritten with x_{n+1}

#pragma clang loop unroll(disable)
    for (int n = 0; n < N_STEPS; ++n) {
        // per-step bias B-frag {t_hi, t_hi, t_lo, 1} on hi cols only
        const float t = (float)n * dtv;
        _Float16 th = (_Float16)t;
        _Float16 tl = (_Float16)(t - (float)th);
        f16x4 bt = (g == 0 && l15 < 8)
                 ? (f16x4){th, th, tl, (_Float16)1.f}
                 : (f16x4){(_Float16)0.f, (_Float16)0.f, (_Float16)0.f, (_Float16)0.f};

        // -------- GEMM1 (transposed): C[h-local][batch-col], bias via MFMA --------
        f32x4 acc1[4];
#pragma unroll
        for (int nt = 0; nt < 4; ++nt)
            acc1[nt] = __builtin_amdgcn_mfma_f32_16x16x16f16(
                __builtin_bit_cast(f16x4, wbs[nt]), bt, (f32x4){0.f, 0.f, 0.f, 0.f}, 0, 0, 0);

        const char* xb = smem + cur * HSLOT + histRd;
        const char* yb = smem + ys * HSLOT + histRd;
#pragma unroll
        for (int ks = 0; ks < 4; ++ks) {
            f16x8 xa = *(const f16x8*)(xb + 64 * ks);
#pragma unroll
            for (int nt = 0; nt < 4; ++nt)
                acc1[nt] = __builtin_amdgcn_mfma_f32_16x16x32_f16(
                    __builtin_bit_cast(f16x8, w1s[nt][ks]), xa, acc1[nt], 0, 0, 0);
        }
#pragma unroll
        for (int ks = 0; ks < 4; ++ks) {
            f16x8 ya = *(const f16x8*)(yb + 64 * ks);
#pragma unroll
            for (int nt = 0; nt < 4; ++nt)
                acc1[nt] = __builtin_amdgcn_mfma_f32_16x16x32_f16(
                    __builtin_bit_cast(f16x8, w1s[nt][ks + 4]), ya, acc1[nt], 0, 0, 0);
        }

        // -------- combine hi+lo cols (DPP), tanh, split -> GEMM2 B-frags in-register --------
        f16x4 pbh[4], pbl[4];
#pragma unroll
        for (int s = 0; s < 4; ++s) {
#pragma unroll
            for (int r = 0; r < 4; ++r) {
                float v = xor8_add(acc1[s][r]);
                float h = tanh_fast(v);
                _Float16 hh = (_Float16)h;
                pbh[s][r] = hh;
                pbl[s][r] = (_Float16)(h - (float)hh);
            }
        }

        // -------- GEMM2: A=W2 (regs), B=pb (regs), K-split; two mt-halves --------
#pragma unroll
        for (int half = 0; half < 2; ++half) {
            f32x4 a2[4];
#pragma unroll
            for (int m = 0; m < 4; ++m) a2[m] = (f32x4){0.f, 0.f, 0.f, 0.f};
#pragma unroll
            for (int s = 0; s < 4; ++s) {
#pragma unroll
                for (int m = 0; m < 4; ++m) {
                    const int mt = 4 * half + m;
                    a2[m] = __builtin_amdgcn_mfma_f32_16x16x16f16(
                        __builtin_bit_cast(f16x4, w2s[mt][s]), pbh[s], a2[m], 0, 0, 0);
                    a2[m] = __builtin_amdgcn_mfma_f32_16x16x16f16(
                        __builtin_bit_cast(f16x4, w2s[mt][s]), pbl[s], a2[m], 0, 0, 0);
                }
            }
            // this lane writes mt = msel + 4*half (static-index select)
            f32x4 v01 = (msel & 1) ? a2[1] : a2[0];
            f32x4 v23 = (msel & 1) ? a2[3] : a2[2];
            f32x4 vw  = (msel & 2) ? v23 : v01;
            *(f32x4*)(smem + slabWr + half * 256) = vw;
        }
        __syncthreads();

        // -------- reduce K-split partials + Euler + emit (1 output/thread) --------
        float acc = 0.f;
#pragma unroll
        for (int wv = 0; wv < 8; ++wv)
            acc += *(const float*)(smem + slabRd + wv * SWSTR);
        const float xn = fmaf(dtv, acc + b2v, xo);
        xo = xn;
        {
            _Float16 hh = (_Float16)xn;
            _Float16 hl = (_Float16)(xn - (float)hh);
            *(short*)(smem + ys * HSLOT + histWr)               = __builtin_bit_cast(short, hh);
            *(short*)(smem + ys * HSLOT + 4 * HSTRIDE + histWr) = __builtin_bit_cast(short, hl);
        }
        out[outIdx + (long)(n + 1) * (B_TOT * D_DIM)] = xn;

        cur = ys;
        ys  = (ys == 10) ? 0 : ys + 1;
        __syncthreads();
    }
}

extern "C" void kernel_launch(void* const* d_in, const int* in_sizes, int n_in,
                              void* d_out, int out_size, void* d_ws, size_t ws_size,
                              hipStream_t stream) {
    (void)in_sizes; (void)n_in; (void)out_size; (void)d_ws; (void)ws_size;
    const float* x0  = (const float*)d_in[0];
    const float* tau = (const float*)d_in[1];
    const float* W1  = (const float*)d_in[2];
    const float* b1  = (const float*)d_in[3];
    const float* W2  = (const float*)d_in[4];
    const float* b2  = (const float*)d_in[5];
    float* out = (float*)d_out;

    ndde_kernel<<<dim3(B_TOT / ROWS), dim3(64 * WAVES), 0, stream>>>(
        x0, tau, W1, b1, W2, b2, out);
}

// Round 7
// 1163.523 us; speedup vs baseline: 1.0495x; 1.0495x over previous
//
#include <hip/hip_runtime.h>

typedef float f32x4 __attribute__((ext_vector_type(4)));
typedef _Float16 f16x8 __attribute__((ext_vector_type(8)));
typedef _Float16 f16x2 __attribute__((ext_vector_type(2)));
typedef int i32x4 __attribute__((ext_vector_type(4)));

#define B_TOT   1024
#define D_DIM   128
#define N_STEPS 500
#define ROWS    4
#define WAVES   8

#define HSTR    272                 // bytes per hist row (128 f16 + 16B pad)
#define HSLOT   (16 * HSTR)         // 16 rows: {x_hi b0-3, 0*4, x_lo b0-3, 0*4}
#define SLABOFF (11 * HSLOT)
#define SBSTR   544                 // slab batch stride (bytes)
#define SWSTR   (4 * SBSTR)         // slab slot stride (4 batches)
#define LDSSZ   (SLABOFF + 8 * SWSTR)

static __device__ __forceinline__ float tanh_fast(float x) {
    float e = __builtin_amdgcn_exp2f(x * 2.885390081777927f);
    return 1.0f - 2.0f * __builtin_amdgcn_rcpf(e + 1.0f);
}
// x + rotate-right-by-4 / by-8 within 16-lane rows (VALU pipe)
static __device__ __forceinline__ float ror_add4(float x) {
    int xi = __builtin_bit_cast(int, x);
    int r4 = __builtin_amdgcn_update_dpp(xi, xi, 0x124, 0xF, 0xF, false);
    float v1 = x + __builtin_bit_cast(float, r4);
    int v1i = __builtin_bit_cast(int, v1);
    int r8 = __builtin_amdgcn_update_dpp(v1i, v1i, 0x128, 0xF, 0xF, false);
    return v1 + __builtin_bit_cast(float, r8);
}
static __device__ __forceinline__ float ror8_add(float x) {
    int xi = __builtin_bit_cast(int, x);
    int r8 = __builtin_amdgcn_update_dpp(xi, xi, 0x128, 0xF, 0xF, false);
    return x + __builtin_bit_cast(float, r8);
}
static __device__ __forceinline__ int packh(_Float16 a, _Float16 b) {
    f16x2 p = (f16x2){a, b};
    return __builtin_bit_cast(int, p);
}

__global__ __launch_bounds__(512, 2) void ndde_kernel(
    const float* __restrict__ x0, const float* __restrict__ tau,
    const float* __restrict__ W1, const float* __restrict__ b1,
    const float* __restrict__ W2, const float* __restrict__ b2,
    float* __restrict__ out)
{
    __shared__ __align__(16) char smem[LDSSZ];

    const int tid = threadIdx.x;
    const int w   = tid >> 6;
    const int l   = tid & 63;
    const int g   = l >> 4;
    const int l15 = l & 15;
    const int r0  = blockIdx.x * ROWS;
    const int rb  = tid >> 7;          // reduce/epilogue identity: batch
    const int rd  = tid & 127;         // and d-column

    const float dtv = tau[0] * 0.1f;

    // ---------- weights -> registers (fp16 frags) ----------
    // GEMM1 A = W1 with pi-permutation: A-row m of tile nt -> h-local
    //   32*(nt>>1) + 8*(m>>2) + 4*(nt&1) + (m&3)
    i32x4 w1s[4][8];   // [nt][ks]  ks 0-3: x cols; 4-7: y cols (128+)
    i32x4 w2s[8][2];   // [mt][s]   A = W2 rows 16mt+l15, k = 64w+32s+8g+j
    i32x4 wbs[4];      // bias frags {wh, wl, wh, b1} on k=0..3 (g==0 lanes)

#pragma unroll
    for (int nt = 0; nt < 4; ++nt) {
        const int hr = 64 * w + 32 * (nt >> 1) + 8 * (l15 >> 2) + 4 * (nt & 1) + (l15 & 3);
        const float* wr = W1 + (long)hr * 257;
#pragma unroll
        for (int ks = 0; ks < 8; ++ks) {
            const int c0 = 32 * ks + 8 * g;
            f16x8 f;
#pragma unroll
            for (int j = 0; j < 8; ++j) f[j] = (_Float16)wr[c0 + j];
            w1s[nt][ks] = __builtin_bit_cast(i32x4, f);
        }
        float wt = wr[256];
        _Float16 wh = (_Float16)wt;
        _Float16 wl = (_Float16)(wt - (float)wh);
        f16x8 ab = (f16x8){0,0,0,0,0,0,0,0};
        if (l < 16) { ab[0] = wh; ab[1] = wl; ab[2] = wh; ab[3] = (_Float16)b1[hr]; }
        wbs[nt] = __builtin_bit_cast(i32x4, ab);
    }
#pragma unroll
    for (int mt = 0; mt < 8; ++mt) {
        const float* wr = W2 + (long)(16 * mt + l15) * 512;
#pragma unroll
        for (int s = 0; s < 2; ++s) {
            const int c0 = 64 * w + 32 * s + 8 * g;
            f16x8 f;
#pragma unroll
            for (int j = 0; j < 8; ++j) f[j] = (_Float16)wr[c0 + j];
            w2s[mt][s] = __builtin_bit_cast(i32x4, f);
        }
    }
#pragma unroll
    for (int nt = 0; nt < 4; ++nt) {
#pragma unroll
        for (int ks = 0; ks < 8; ++ks) asm volatile("" : "+v"(w1s[nt][ks]));
        asm volatile("" : "+v"(wbs[nt]));
    }
#pragma unroll
    for (int mt = 0; mt < 8; ++mt) {
        asm volatile("" : "+v"(w2s[mt][0]));
        asm volatile("" : "+v"(w2s[mt][1]));
    }

    const float b2v = b2[rd];
    float xo = x0[(long)(r0 + rb) * D_DIM + rd];

    // ---------- init hist ring (incl. zero rows) + out[0] ----------
    {
        _Float16 hh = (_Float16)xo;
        _Float16 hl = (_Float16)(xo - (float)hh);
        const int zrow = 4 + rb;       // zero rows 4-7 and 12-15
        for (int s = 0; s < 11; ++s) {
            char* sl = smem + s * HSLOT;
            *(short*)(sl + rb * HSTR + 2 * rd)         = __builtin_bit_cast(short, hh);
            *(short*)(sl + (rb + 8) * HSTR + 2 * rd)   = __builtin_bit_cast(short, hl);
            *(short*)(sl + zrow * HSTR + 2 * rd)       = 0;
            *(short*)(sl + (zrow + 8) * HSTR + 2 * rd) = 0;
        }
        out[(long)(r0 + rb) * D_DIM + rd] = xo;
    }
    __syncthreads();

    // invariant lane offsets
    const int histRdX = l15 * HSTR + 16 * g;          // + slot*HSLOT + 64*ks
    const int histRdY = (l15 ^ 4) * HSTR + 16 * g;
    const int slabWr  = SLABOFF + w * SWSTR + l15 * SBSTR + 16 * g;  // + 256*half + 64*m
    const int slabRd  = SLABOFF + rb * SBSTR + 4 * rd;               // + slot*SWSTR
    const int histWr  = rb * HSTR + 2 * rd;            // + slot*HSLOT (+8*HSTR lo)
    const bool wact   = (l15 < 4);                     // slab writer lanes
    const bool selhi  = (l15 < 8);
    float* po = out + (long)(B_TOT * D_DIM) + (long)(r0 + rb) * D_DIM + rd;

    int cur = 0, ys = 1;

#pragma clang loop unroll(disable)
    for (int n = 0; n < N_STEPS; ++n) {
        // ---- per-step bias B-frag: cols 0-3, k = {th, th, tl, 1} ----
        const float t = (float)n * dtv;
        _Float16 th = (_Float16)t;
        _Float16 tl = (_Float16)(t - (float)th);
        int b0  = (l < 4) ? packh(th, th) : 0;
        int b1i = (l < 4) ? packh(tl, (_Float16)1.0f) : 0;
        i32x4 btv = (i32x4){b0, b1i, 0, 0};
        f16x8 bt = __builtin_bit_cast(f16x8, btv);

        // ---- GEMM1: acc1[nt] = bias + W1x@[xcols] + W1y@[ycols] ----
        f32x4 acc1[4];
#pragma unroll
        for (int nt = 0; nt < 4; ++nt)
            acc1[nt] = __builtin_amdgcn_mfma_f32_16x16x32_f16(
                __builtin_bit_cast(f16x8, wbs[nt]), bt, (f32x4){0.f,0.f,0.f,0.f}, 0, 0, 0);

        const char* xb = smem + cur * HSLOT + histRdX;
        const char* yb = smem + ys * HSLOT + histRdY;
#pragma unroll
        for (int ks = 0; ks < 4; ++ks) {
            f16x8 xa = *(const f16x8*)(xb + 64 * ks);
#pragma unroll
            for (int nt = 0; nt < 4; ++nt)
                acc1[nt] = __builtin_amdgcn_mfma_f32_16x16x32_f16(
                    __builtin_bit_cast(f16x8, w1s[nt][ks]), xa, acc1[nt], 0, 0, 0);
        }
#pragma unroll
        for (int ks = 0; ks < 4; ++ks) {
            f16x8 ya = *(const f16x8*)(yb + 64 * ks);
#pragma unroll
            for (int nt = 0; nt < 4; ++nt)
                acc1[nt] = __builtin_amdgcn_mfma_f32_16x16x32_f16(
                    __builtin_bit_cast(f16x8, w1s[nt][ks + 4]), ya, acc1[nt], 0, 0, 0);
        }

        // ---- combine col-groups (2 DPP adds), tanh, hi/lo split ----
        int hhp[4][2], hlp[4][2];
#pragma unroll
        for (int nt = 0; nt < 4; ++nt) {
            float h0 = tanh_fast(ror_add4(acc1[nt][0]));
            float h1 = tanh_fast(ror_add4(acc1[nt][1]));
            float h2 = tanh_fast(ror_add4(acc1[nt][2]));
            float h3 = tanh_fast(ror_add4(acc1[nt][3]));
            _Float16 p0 = (_Float16)h0, p1 = (_Float16)h1;
            _Float16 p2 = (_Float16)h2, p3 = (_Float16)h3;
            hhp[nt][0] = packh(p0, p1);
            hhp[nt][1] = packh(p2, p3);
            hlp[nt][0] = packh((_Float16)(h0 - (float)p0), (_Float16)(h1 - (float)p1));
            hlp[nt][1] = packh((_Float16)(h2 - (float)p2), (_Float16)(h3 - (float)p3));
        }
        i32x4 pb[2];
#pragma unroll
        for (int s = 0; s < 2; ++s)
            pb[s] = (i32x4){ selhi ? hhp[2*s][0]   : hlp[2*s][0],
                             selhi ? hhp[2*s][1]   : hlp[2*s][1],
                             selhi ? hhp[2*s+1][0] : hlp[2*s+1][0],
                             selhi ? hhp[2*s+1][1] : hlp[2*s+1][1] };

        // ---- GEMM2 (two mt-halves, K=64 split): hi+lo combined, slab write ----
#pragma unroll
        for (int half = 0; half < 2; ++half) {
            f32x4 a2[4];
#pragma unroll
            for (int m = 0; m < 4; ++m) a2[m] = (f32x4){0.f,0.f,0.f,0.f};
#pragma unroll
            for (int s = 0; s < 2; ++s)
#pragma unroll
                for (int m = 0; m < 4; ++m)
                    a2[m] = __builtin_amdgcn_mfma_f32_16x16x32_f16(
                        __builtin_bit_cast(f16x8, w2s[4*half+m][s]),
                        __builtin_bit_cast(f16x8, pb[s]), a2[m], 0, 0, 0);
#pragma unroll
            for (int m = 0; m < 4; ++m) {
                f32x4 s4;
#pragma unroll
                for (int r = 0; r < 4; ++r) s4[r] = ror8_add(a2[m][r]);  // col l += col l+8 (hi+lo)
                if (wact)
                    *(f32x4*)(smem + slabWr + 256 * half + 64 * m) = s4;
            }
        }
        __syncthreads();

        // ---- reduce 8 K-split partials + Euler + hist/out emit ----
        float acc = 0.f;
#pragma unroll
        for (int sv = 0; sv < 8; ++sv)
            acc += *(const float*)(smem + slabRd + sv * SWSTR);
        const float xn = fmaf(dtv, acc + b2v, xo);
        xo = xn;
        {
            _Float16 hh = (_Float16)xn;
            _Float16 hl = (_Float16)(xn - (float)hh);
            char* sl = smem + ys * HSLOT;
            *(short*)(sl + histWr)            = __builtin_bit_cast(short, hh);
            *(short*)(sl + 8 * HSTR + histWr) = __builtin_bit_cast(short, hl);
        }
        *po = xn;
        po += B_TOT * D_DIM;

        cur = ys;
        ys  = (ys == 10) ? 0 : ys + 1;
        __syncthreads();
    }
}

extern "C" void kernel_launch(void* const* d_in, const int* in_sizes, int n_in,
                              void* d_out, int out_size, void* d_ws, size_t ws_size,
                              hipStream_t stream) {
    (void)in_sizes; (void)n_in; (void)out_size; (void)d_ws; (void)ws_size;
    const float* x0  = (const float*)d_in[0];
    const float* tau = (const float*)d_in[1];
    const float* W1  = (const float*)d_in[2];
    const float* b1  = (const float*)d_in[3];
    const float* W2  = (const float*)d_in[4];
    const float* b2  = (const float*)d_in[5];
    float* out = (float*)d_out;

    ndde_kernel<<<dim3(B_TOT / ROWS), dim3(64 * WAVES), 0, stream>>>(
        x0, tau, W1, b1, W2, b2, out);
}

// Round 8
// 1163.091 us; speedup vs baseline: 1.0499x; 1.0004x over previous
//
#include <hip/hip_runtime.h>

typedef float f32x4 __attribute__((ext_vector_type(4)));
typedef _Float16 f16x8 __attribute__((ext_vector_type(8)));
typedef _Float16 f16x2 __attribute__((ext_vector_type(2)));
typedef int i32x4 __attribute__((ext_vector_type(4)));

#define B_TOT   1024
#define D_DIM   128
#define N_STEPS 500
#define ROWS    4
#define WAVES   8

#define HSTR    272                 // bytes per hist row (128 f16 + 16B pad)
#define HSLOT   (16 * HSTR)         // 16 rows: {x_hi b0-3, 0*4, x_lo b0-3, 0*4}
#define SLABOFF (11 * HSLOT)
#define SBSTR   544                 // slab batch stride (bytes)
#define SWSTR   (4 * SBSTR)         // slab slot stride (4 batches)
#define LDSSZ   (SLABOFF + 8 * SWSTR)

static __device__ __forceinline__ float tanh_fast(float x) {
    float e = __builtin_amdgcn_exp2f(x * 2.885390081777927f);
    return 1.0f - 2.0f * __builtin_amdgcn_rcpf(e + 1.0f);
}
// x + rotate-right-by-4 / by-8 within 16-lane rows (VALU pipe)
static __device__ __forceinline__ float ror_add4(float x) {
    int xi = __builtin_bit_cast(int, x);
    int r4 = __builtin_amdgcn_update_dpp(xi, xi, 0x124, 0xF, 0xF, false);
    float v1 = x + __builtin_bit_cast(float, r4);
    int v1i = __builtin_bit_cast(int, v1);
    int r8 = __builtin_amdgcn_update_dpp(v1i, v1i, 0x128, 0xF, 0xF, false);
    return v1 + __builtin_bit_cast(float, r8);
}
static __device__ __forceinline__ float ror8_add(float x) {
    int xi = __builtin_bit_cast(int, x);
    int r8 = __builtin_amdgcn_update_dpp(xi, xi, 0x128, 0xF, 0xF, false);
    return x + __builtin_bit_cast(float, r8);
}
static __device__ __forceinline__ int packh(_Float16 a, _Float16 b) {
    f16x2 p = (f16x2){a, b};
    return __builtin_bit_cast(int, p);
}
// LDS-only barrier: wait for DS ops, NOT for in-flight global stores
// (__syncthreads would emit s_waitcnt vmcnt(0) and stall ~HBM-store latency)
static __device__ __forceinline__ void barrier_lds() {
    asm volatile("s_waitcnt lgkmcnt(0)" ::: "memory");
    __builtin_amdgcn_s_barrier();
}

__global__ __launch_bounds__(512, 2) void ndde_kernel(
    const float* __restrict__ x0, const float* __restrict__ tau,
    const float* __restrict__ W1, const float* __restrict__ b1,
    const float* __restrict__ W2, const float* __restrict__ b2,
    float* __restrict__ out)
{
    __shared__ __align__(16) char smem[LDSSZ];

    const int tid = threadIdx.x;
    const int w   = tid >> 6;
    const int l   = tid & 63;
    const int g   = l >> 4;
    const int l15 = l & 15;
    const int r0  = blockIdx.x * ROWS;
    const int rb  = tid >> 7;          // reduce/epilogue identity: batch
    const int rd  = tid & 127;         // and d-column

    const float dtv = tau[0] * 0.1f;

    // ---------- weights -> registers (fp16 frags) ----------
    // GEMM1 A = W1 with pi-permutation: A-row m of tile nt -> h-local
    //   32*(nt>>1) + 8*(m>>2) + 4*(nt&1) + (m&3)
    i32x4 w1s[4][8];   // [nt][ks]  ks 0-3: x cols; 4-7: y cols (128+)
    i32x4 w2s[8][2];   // [mt][s]   A = W2 rows 16mt+l15, k = 64w+32s+8g+j
    i32x4 wbs[4];      // bias frags {wh, wl, wh, b1} on k=0..3 (g==0 lanes)

#pragma unroll
    for (int nt = 0; nt < 4; ++nt) {
        const int hr = 64 * w + 32 * (nt >> 1) + 8 * (l15 >> 2) + 4 * (nt & 1) + (l15 & 3);
        const float* wr = W1 + (long)hr * 257;
#pragma unroll
        for (int ks = 0; ks < 8; ++ks) {
            const int c0 = 32 * ks + 8 * g;
            f16x8 f;
#pragma unroll
            for (int j = 0; j < 8; ++j) f[j] = (_Float16)wr[c0 + j];
            w1s[nt][ks] = __builtin_bit_cast(i32x4, f);
        }
        float wt = wr[256];
        _Float16 wh = (_Float16)wt;
        _Float16 wl = (_Float16)(wt - (float)wh);
        f16x8 ab = (f16x8){0,0,0,0,0,0,0,0};
        if (l < 16) { ab[0] = wh; ab[1] = wl; ab[2] = wh; ab[3] = (_Float16)b1[hr]; }
        wbs[nt] = __builtin_bit_cast(i32x4, ab);
    }
#pragma unroll
    for (int mt = 0; mt < 8; ++mt) {
        const float* wr = W2 + (long)(16 * mt + l15) * 512;
#pragma unroll
        for (int s = 0; s < 2; ++s) {
            const int c0 = 64 * w + 32 * s + 8 * g;
            f16x8 f;
#pragma unroll
            for (int j = 0; j < 8; ++j) f[j] = (_Float16)wr[c0 + j];
            w2s[mt][s] = __builtin_bit_cast(i32x4, f);
        }
    }
#pragma unroll
    for (int nt = 0; nt < 4; ++nt) {
#pragma unroll
        for (int ks = 0; ks < 8; ++ks) asm volatile("" : "+v"(w1s[nt][ks]));
        asm volatile("" : "+v"(wbs[nt]));
    }
#pragma unroll
    for (int mt = 0; mt < 8; ++mt) {
        asm volatile("" : "+v"(w2s[mt][0]));
        asm volatile("" : "+v"(w2s[mt][1]));
    }

    const float b2v = b2[rd];
    float xo = x0[(long)(r0 + rb) * D_DIM + rd];

    // ---------- init hist ring (incl. zero rows) + out[0] ----------
    {
        _Float16 hh = (_Float16)xo;
        _Float16 hl = (_Float16)(xo - (float)hh);
        const int zrow = 4 + rb;       // zero rows 4-7 and 12-15
        for (int s = 0; s < 11; ++s) {
            char* sl = smem + s * HSLOT;
            *(short*)(sl + rb * HSTR + 2 * rd)         = __builtin_bit_cast(short, hh);
            *(short*)(sl + (rb + 8) * HSTR + 2 * rd)   = __builtin_bit_cast(short, hl);
            *(short*)(sl + zrow * HSTR + 2 * rd)       = 0;
            *(short*)(sl + (zrow + 8) * HSTR + 2 * rd) = 0;
        }
        out[(long)(r0 + rb) * D_DIM + rd] = xo;
    }
    __syncthreads();

    // invariant lane offsets
    const int histRdX = l15 * HSTR + 16 * g;          // + slot*HSLOT + 64*ks
    const int histRdY = (l15 ^ 4) * HSTR + 16 * g;
    const int slabWr  = SLABOFF + w * SWSTR + l15 * SBSTR + 16 * g;  // + 256*half + 64*m
    const int slabRd  = SLABOFF + rb * SBSTR + 4 * rd;               // + slot*SWSTR
    const int histWr  = rb * HSTR + 2 * rd;            // + slot*HSLOT (+8*HSTR lo)
    const bool wact   = (l15 < 4);                     // slab writer lanes
    const bool selhi  = (l15 < 8);
    float* po = out + (long)(B_TOT * D_DIM) + (long)(r0 + rb) * D_DIM + rd;

    int cur = 0, ys = 1;

#pragma clang loop unroll(disable)
    for (int n = 0; n < N_STEPS; ++n) {
        // ---- per-step bias B-frag: cols 0-3, k = {th, th, tl, 1} ----
        const float t = (float)n * dtv;
        _Float16 th = (_Float16)t;
        _Float16 tl = (_Float16)(t - (float)th);
        int b0  = (l < 4) ? packh(th, th) : 0;
        int b1i = (l < 4) ? packh(tl, (_Float16)1.0f) : 0;
        i32x4 btv = (i32x4){b0, b1i, 0, 0};
        f16x8 bt = __builtin_bit_cast(f16x8, btv);

        // ---- GEMM1: acc1[nt] = bias + W1x@[xcols] + W1y@[ycols] ----
        f32x4 acc1[4];
#pragma unroll
        for (int nt = 0; nt < 4; ++nt)
            acc1[nt] = __builtin_amdgcn_mfma_f32_16x16x32_f16(
                __builtin_bit_cast(f16x8, wbs[nt]), bt, (f32x4){0.f,0.f,0.f,0.f}, 0, 0, 0);

        const char* xb = smem + cur * HSLOT + histRdX;
        const char* yb = smem + ys * HSLOT + histRdY;
#pragma unroll
        for (int ks = 0; ks < 4; ++ks) {
            f16x8 xa = *(const f16x8*)(xb + 64 * ks);
#pragma unroll
            for (int nt = 0; nt < 4; ++nt)
                acc1[nt] = __builtin_amdgcn_mfma_f32_16x16x32_f16(
                    __builtin_bit_cast(f16x8, w1s[nt][ks]), xa, acc1[nt], 0, 0, 0);
        }
#pragma unroll
        for (int ks = 0; ks < 4; ++ks) {
            f16x8 ya = *(const f16x8*)(yb + 64 * ks);
#pragma unroll
            for (int nt = 0; nt < 4; ++nt)
                acc1[nt] = __builtin_amdgcn_mfma_f32_16x16x32_f16(
                    __builtin_bit_cast(f16x8, w1s[nt][ks + 4]), ya, acc1[nt], 0, 0, 0);
        }

        // ---- combine col-groups (2 DPP adds), tanh, hi/lo split ----
        int hhp[4][2], hlp[4][2];
#pragma unroll
        for (int nt = 0; nt < 4; ++nt) {
            float h0 = tanh_fast(ror_add4(acc1[nt][0]));
            float h1 = tanh_fast(ror_add4(acc1[nt][1]));
            float h2 = tanh_fast(ror_add4(acc1[nt][2]));
            float h3 = tanh_fast(ror_add4(acc1[nt][3]));
            _Float16 p0 = (_Float16)h0, p1 = (_Float16)h1;
            _Float16 p2 = (_Float16)h2, p3 = (_Float16)h3;
            hhp[nt][0] = packh(p0, p1);
            hhp[nt][1] = packh(p2, p3);
            hlp[nt][0] = packh((_Float16)(h0 - (float)p0), (_Float16)(h1 - (float)p1));
            hlp[nt][1] = packh((_Float16)(h2 - (float)p2), (_Float16)(h3 - (float)p3));
        }
        i32x4 pb[2];
#pragma unroll
        for (int s = 0; s < 2; ++s)
            pb[s] = (i32x4){ selhi ? hhp[2*s][0]   : hlp[2*s][0],
                             selhi ? hhp[2*s][1]   : hlp[2*s][1],
                             selhi ? hhp[2*s+1][0] : hlp[2*s+1][0],
                             selhi ? hhp[2*s+1][1] : hlp[2*s+1][1] };

        // ---- GEMM2 (two mt-halves, K=64 split): hi+lo combined, slab write ----
#pragma unroll
        for (int half = 0; half < 2; ++half) {
            f32x4 a2[4];
#pragma unroll
            for (int m = 0; m < 4; ++m) a2[m] = (f32x4){0.f,0.f,0.f,0.f};
#pragma unroll
            for (int s = 0; s < 2; ++s)
#pragma unroll
                for (int m = 0; m < 4; ++m)
                    a2[m] = __builtin_amdgcn_mfma_f32_16x16x32_f16(
                        __builtin_bit_cast(f16x8, w2s[4*half+m][s]),
                        __builtin_bit_cast(f16x8, pb[s]), a2[m], 0, 0, 0);
#pragma unroll
            for (int m = 0; m < 4; ++m) {
                f32x4 s4;
#pragma unroll
                for (int r = 0; r < 4; ++r) s4[r] = ror8_add(a2[m][r]);  // col l += col l+8 (hi+lo)
                if (wact)
                    *(f32x4*)(smem + slabWr + 256 * half + 64 * m) = s4;
            }
        }
        barrier_lds();

        // ---- reduce 8 K-split partials + Euler + hist/out emit ----
        float acc = 0.f;
#pragma unroll
        for (int sv = 0; sv < 8; ++sv)
            acc += *(const float*)(smem + slabRd + sv * SWSTR);
        const float xn = fmaf(dtv, acc + b2v, xo);
        xo = xn;
        {
            _Float16 hh = (_Float16)xn;
            _Float16 hl = (_Float16)(xn - (float)hh);
            char* sl = smem + ys * HSLOT;
            *(short*)(sl + histWr)            = __builtin_bit_cast(short, hh);
            *(short*)(sl + 8 * HSTR + histWr) = __builtin_bit_cast(short, hl);
        }
        *po = xn;            // async HBM store — barrier below does NOT drain vmcnt
        po += B_TOT * D_DIM;

        cur = ys;
        ys  = (ys == 10) ? 0 : ys + 1;
        barrier_lds();
    }
}

extern "C" void kernel_launch(void* const* d_in, const int* in_sizes, int n_in,
                              void* d_out, int out_size, void* d_ws, size_t ws_size,
                              hipStream_t stream) {
    (void)in_sizes; (void)n_in; (void)out_size; (void)d_ws; (void)ws_size;
    const float* x0  = (const float*)d_in[0];
    const float* tau = (const float*)d_in[1];
    const float* W1  = (const float*)d_in[2];
    const float* b1  = (const float*)d_in[3];
    const float* W2  = (const float*)d_in[4];
    const float* b2  = (const float*)d_in[5];
    float* out = (float*)d_out;

    ndde_kernel<<<dim3(B_TOT / ROWS), dim3(64 * WAVES), 0, stream>>>(
        x0, tau, W1, b1, W2, b2, out);
}